// Round 5
// baseline (521.771 us; speedup 1.0000x reference)
//
#include <hip/hip_runtime.h>

#define D 64

__device__ __forceinline__ int get_xcc_id() {
    int x;
    asm volatile("s_getreg_b32 %0, hwreg(HW_REG_XCC_ID)" : "=s"(x));
    return x & 7;
}

// ---------------- setup kernels ----------------

// Per-XCD private histogram slices updated with WORKGROUP-scope (L2-local)
// atomics: all updaters of slice c run on XCD c, so XCD-L2 atomicity suffices;
// cross-dispatch visibility comes from the end-of-dispatch agent release (the
// same mechanism every producer->consumer kernel chain here already relies on).
// The atomicAdd return is the edge's within-slice slot; xcd packed in top bits.
__global__ void hist_slot_kernel(const int* __restrict__ src, const int* __restrict__ dst,
                                 int* __restrict__ slice_src,  // [8][N]
                                 int* __restrict__ slice_dst,  // [8][N]
                                 int* __restrict__ slot, int E, int N) {
    int i = blockIdx.x * blockDim.x + threadIdx.x;
    if (i >= E) return;
    int c = get_xcc_id();
    int s = src[i];
    int d = dst[i];
    __hip_atomic_fetch_add(&slice_src[c * N + s], 1, __ATOMIC_RELAXED,
                           __HIP_MEMORY_SCOPE_WORKGROUP);
    int sl = __hip_atomic_fetch_add(&slice_dst[c * N + d], 1, __ATOMIC_RELAXED,
                                    __HIP_MEMORY_SCOPE_WORKGROUP);
    slot[i] = sl | (c << 28);  // E < 2^28, c < 8
}

// Merge the 8 slices: total degrees, norms, and per-(node,xcd) base offsets
// (within-node exclusive prefix over xcd; row_ptr added later in scan3).
__global__ void merge_kernel(const int* __restrict__ slice_src, const int* __restrict__ slice_dst,
                             int* __restrict__ deg_dst, int* __restrict__ base8,
                             float* __restrict__ out_norm, float* __restrict__ in_norm, int N) {
    int v = blockIdx.x * blockDim.x + threadIdx.x;
    if (v >= N) return;
    int ssum = 0;
#pragma unroll
    for (int c = 0; c < 8; c++) ssum += slice_src[c * N + v];
    int run = 0;
    int pre[8];
#pragma unroll
    for (int c = 0; c < 8; c++) { pre[c] = run; run += slice_dst[c * N + v]; }
#pragma unroll
    for (int c = 0; c < 8; c++) base8[v * 8 + c] = pre[c];
    deg_dst[v] = run;
    out_norm[v] = rsqrtf((float)max(ssum, 1));
    in_norm[v] = rsqrtf((float)max(run, 1));
}

// Scan step 1: per-block (1024 elements) totals of deg_dst.
__global__ void scan1_kernel(const int* __restrict__ deg, int* __restrict__ blk_tot, int n) {
    __shared__ int sdata[256];
    int tid = threadIdx.x;
    int base = blockIdx.x * 1024 + tid * 4;
    int s = 0;
#pragma unroll
    for (int j = 0; j < 4; j++) {
        int idx = base + j;
        s += (idx < n) ? deg[idx] : 0;
    }
    sdata[tid] = s;
    __syncthreads();
    for (int off = 128; off > 0; off >>= 1) {
        if (tid < off) sdata[tid] += sdata[tid + off];
        __syncthreads();
    }
    if (tid == 0) blk_tot[blockIdx.x] = sdata[0];
}

// Scan step 2: exclusive scan of block totals (single block, nb <= 1024).
__global__ void scan2_kernel(int* __restrict__ blk_tot, int nb) {
    __shared__ int tmp[1024];
    int tid = threadIdx.x;
    int v = (tid < nb) ? blk_tot[tid] : 0;
    tmp[tid] = v;
    __syncthreads();
    int val = v;
    for (int off = 1; off < 1024; off <<= 1) {
        int add = (tid >= off) ? tmp[tid - off] : 0;
        __syncthreads();
        val += add;
        tmp[tid] = val;
        __syncthreads();
    }
    if (tid < nb) blk_tot[tid] = val - v;  // exclusive
}

// Scan step 3: write exclusive row_ptr and fold it into the base8 table.
__global__ void scan3_kernel(const int* __restrict__ deg_dst, const int* __restrict__ blk_tot,
                             int* __restrict__ row_ptr, int* __restrict__ base8,
                             int n, int E) {
    __shared__ int sdata[256];
    int tid = threadIdx.x;
    int base = blockIdx.x * 1024 + tid * 4;
    int v[4];
    int s = 0;
#pragma unroll
    for (int j = 0; j < 4; j++) {
        int idx = base + j;
        v[j] = (idx < n) ? deg_dst[idx] : 0;
        s += v[j];
    }
    sdata[tid] = s;
    __syncthreads();
    int val = s;
    for (int off = 1; off < 256; off <<= 1) {
        int add = (tid >= off) ? sdata[tid - off] : 0;
        __syncthreads();
        val += add;
        sdata[tid] = val;
        __syncthreads();
    }
    int excl = blk_tot[blockIdx.x] + val - s;
#pragma unroll
    for (int j = 0; j < 4; j++) {
        int idx = base + j;
        if (idx < n) {
            row_ptr[idx] = excl;
#pragma unroll
            for (int c = 0; c < 8; c++) base8[idx * 8 + c] += excl;
        }
        excl += v[j];
    }
    if (blockIdx.x == 0 && tid == 0) row_ptr[n] = E;
}

// Atomic-free CSR fill: global position = base8[dst][xcd] + within-slice slot.
__global__ void fill_csr_kernel(const int* __restrict__ src, const int* __restrict__ dst,
                                const int* __restrict__ base8, const int* __restrict__ slot,
                                int* __restrict__ csr_src, int E) {
    int i = blockIdx.x * blockDim.x + threadIdx.x;
    if (i < E) {
        unsigned sl = (unsigned)slot[i];
        int c = sl >> 28;
        int within = sl & 0x0FFFFFFF;
        csr_src[base8[dst[i] * 8 + c] + within] = src[i];
    }
}

// ---------------- dense GEMM: Y[row] = (X[row] @ W) * (scale ? out_norm[row] : 1) ----------
__global__ __launch_bounds__(256) void gemm_kernel(
    const float* __restrict__ X, const float* __restrict__ W,
    const float* __restrict__ out_norm, float* __restrict__ Y,
    int n, int scale_rows) {
    int lane = threadIdx.x & 63;
    int wid = blockIdx.x * 4 + (threadIdx.x >> 6);
    int base = wid * 16;
    if (base >= n) return;

    float w[D];
#pragma unroll
    for (int k = 0; k < D; k++) w[k] = W[k * D + lane];

    int m = min(16, n - base);
    for (int i = 0; i < m; i++) {
        int row = base + i;
        const float* Xr = X + (size_t)__builtin_amdgcn_readfirstlane(row) * D;
        float o0 = 0.f, o1 = 0.f, o2 = 0.f, o3 = 0.f;
#pragma unroll
        for (int k = 0; k < D; k += 4) {
            o0 = fmaf(Xr[k + 0], w[k + 0], o0);
            o1 = fmaf(Xr[k + 1], w[k + 1], o1);
            o2 = fmaf(Xr[k + 2], w[k + 2], o2);
            o3 = fmaf(Xr[k + 3], w[k + 3], o3);
        }
        float o = (o0 + o1) + (o2 + o3);
        if (scale_rows) o *= out_norm[row];
        Y[(size_t)row * D + lane] = o;
    }
}

// ---------------- gather-sum: h[v] = post( in_norm[v] * sum_{e} P[src(e)] + b ) ----------
__global__ __launch_bounds__(256) void gather_kernel(
    const float4* __restrict__ P4, const int* __restrict__ csr_src,
    const int* __restrict__ row_ptr, const float* __restrict__ in_norm,
    const float* __restrict__ out_norm, const float* __restrict__ bias,
    float4* __restrict__ out4, int n, int relu_scale) {
    int tid = threadIdx.x;
    int lane = tid & 63;
    int v = blockIdx.x * 4 + (tid >> 6);
    if (v >= n) return;

    int begin = row_ptr[v];
    int end = row_ptr[v + 1];
    int eg = lane >> 4;   // edge group 0..3
    int fl = lane & 15;   // float4 index within row

    float inv = in_norm[v];
    float sc = relu_scale ? out_norm[v] : 1.f;
    float4 b4 = ((const float4*)bias)[fl];

    float4 acc0 = make_float4(0.f, 0.f, 0.f, 0.f);
    float4 acc1 = make_float4(0.f, 0.f, 0.f, 0.f);

    for (int base_e = begin; base_e < end; base_e += 16) {
        int e0 = base_e + eg;
        int e1 = e0 + 4;
        int e2 = e0 + 8;
        int e3 = e0 + 12;
        int j0 = (e0 < end) ? csr_src[e0] : -1;
        int j1 = (e1 < end) ? csr_src[e1] : -1;
        int j2 = (e2 < end) ? csr_src[e2] : -1;
        int j3 = (e3 < end) ? csr_src[e3] : -1;
        if (j0 >= 0) {
            float4 a = P4[(size_t)j0 * 16 + fl];
            acc0.x += a.x; acc0.y += a.y; acc0.z += a.z; acc0.w += a.w;
        }
        if (j1 >= 0) {
            float4 a = P4[(size_t)j1 * 16 + fl];
            acc1.x += a.x; acc1.y += a.y; acc1.z += a.z; acc1.w += a.w;
        }
        if (j2 >= 0) {
            float4 a = P4[(size_t)j2 * 16 + fl];
            acc0.x += a.x; acc0.y += a.y; acc0.z += a.z; acc0.w += a.w;
        }
        if (j3 >= 0) {
            float4 a = P4[(size_t)j3 * 16 + fl];
            acc1.x += a.x; acc1.y += a.y; acc1.z += a.z; acc1.w += a.w;
        }
    }
    acc0.x += acc1.x; acc0.y += acc1.y; acc0.z += acc1.z; acc0.w += acc1.w;

    acc0.x += __shfl_down(acc0.x, 32); acc0.y += __shfl_down(acc0.y, 32);
    acc0.z += __shfl_down(acc0.z, 32); acc0.w += __shfl_down(acc0.w, 32);
    acc0.x += __shfl_down(acc0.x, 16); acc0.y += __shfl_down(acc0.y, 16);
    acc0.z += __shfl_down(acc0.z, 16); acc0.w += __shfl_down(acc0.w, 16);

    if (eg == 0) {
        float4 o;
        o.x = fmaf(acc0.x, inv, b4.x);
        o.y = fmaf(acc0.y, inv, b4.y);
        o.z = fmaf(acc0.z, inv, b4.z);
        o.w = fmaf(acc0.w, inv, b4.w);
        if (relu_scale) {
            o.x = fmaxf(o.x, 0.f) * sc;
            o.y = fmaxf(o.y, 0.f) * sc;
            o.z = fmaxf(o.z, 0.f) * sc;
            o.w = fmaxf(o.w, 0.f) * sc;
        }
        out4[(size_t)v * 16 + fl] = o;
    }
}

// ---------------- launch ----------------

extern "C" void kernel_launch(void* const* d_in, const int* in_sizes, int n_in,
                              void* d_out, int out_size, void* d_ws, size_t ws_size,
                              hipStream_t stream) {
    const float* x  = (const float*)d_in[0];
    const int* src  = (const int*)d_in[1];
    const int* dst  = (const int*)d_in[2];
    const float* W1 = (const float*)d_in[3];
    const float* b1 = (const float*)d_in[4];
    const float* W2 = (const float*)d_in[5];
    const float* b2 = (const float*)d_in[6];
    const float* W3 = (const float*)d_in[7];
    const float* b3 = (const float*)d_in[8];

    const int N = in_sizes[0] / D;
    const int E = in_sizes[1];

    char* ws = (char*)d_ws;
    size_t off = 0;
    auto alloc = [&](size_t elems) -> void* {
        void* p = (void*)(ws + off);
        off += ((elems + 3) / 4) * 16;  // pad to 16B
        return p;
    };
    int* deg_dst   = (int*)alloc(N);
    int* row_ptr   = (int*)alloc(N + 1);
    int* blk_tot   = (int*)alloc(1024);
    float* out_nrm = (float*)alloc(N);
    float* in_nrm  = (float*)alloc(N);
    int* slot      = (int*)alloc(E);
    int* csr_src   = (int*)alloc(E);
    float* bufP    = (float*)alloc((size_t)N * D);  // transformed features
    float* bufH    = (float*)alloc((size_t)N * D);  // hidden state

    // Overlays (dead before the layer kernels first write their hosts):
    // slices [8][N]x2 live in bufP (first written by gemm #1, after merge);
    // base8 [N*8] lives in bufH (first written by gather #1, after fill_csr).
    int* slice_src = (int*)bufP;            // 8*N ints
    int* slice_dst = slice_src + 8 * N;     // 8*N ints  (total 6.4 MB of 25.6)
    int* base8     = (int*)bufH;            // 8*N ints

    const int B = 256;
    hipMemsetAsync(slice_src, 0, (size_t)16 * N * sizeof(int), stream);
    hist_slot_kernel<<<(E + B - 1) / B, B, 0, stream>>>(src, dst, slice_src, slice_dst,
                                                        slot, E, N);
    merge_kernel<<<(N + B - 1) / B, B, 0, stream>>>(slice_src, slice_dst, deg_dst,
                                                    base8, out_nrm, in_nrm, N);

    int nb = (N + 1023) / 1024;
    scan1_kernel<<<nb, 256, 0, stream>>>(deg_dst, blk_tot, N);
    scan2_kernel<<<1, 1024, 0, stream>>>(blk_tot, nb);
    scan3_kernel<<<nb, 256, 0, stream>>>(deg_dst, blk_tot, row_ptr, base8, N, E);

    fill_csr_kernel<<<(E + B - 1) / B, B, 0, stream>>>(src, dst, base8, slot,
                                                       csr_src, E);

    int ggrid = (N / 16 + 3) / 4;           // 16 rows/wave, 4 waves/block
    int sgrid = (N + 3) / 4;                // 1 node/wave, 4 waves/block

    // layer 1: P = (X W1) * out_norm ; h1 = relu(in_norm*(A P) + b1) * out_norm
    gemm_kernel<<<ggrid, 256, 0, stream>>>(x, W1, out_nrm, bufP, N, 1);
    gather_kernel<<<sgrid, 256, 0, stream>>>((const float4*)bufP, csr_src, row_ptr,
                                             in_nrm, out_nrm, b1, (float4*)bufH, N, 1);
    // layer 2
    gemm_kernel<<<ggrid, 256, 0, stream>>>(bufH, W2, out_nrm, bufP, N, 0);
    gather_kernel<<<sgrid, 256, 0, stream>>>((const float4*)bufP, csr_src, row_ptr,
                                             in_nrm, out_nrm, b2, (float4*)bufH, N, 1);
    // layer 3: final — no relu, no pre-scale
    gemm_kernel<<<ggrid, 256, 0, stream>>>(bufH, W3, out_nrm, bufP, N, 0);
    gather_kernel<<<sgrid, 256, 0, stream>>>((const float4*)bufP, csr_src, row_ptr,
                                             in_nrm, out_nrm, b3, (float4*)d_out, N, 0);
}

// Round 6
// 453.951 us; speedup vs baseline: 1.1494x; 1.1494x over previous
//
#include <hip/hip_runtime.h>

#define D 64

// ---------------- fused: degree histograms (+slot capture) & layer-1 GEMM ----------------
// hist part is memory-side-atomic throughput bound (~90 us for 2M atomics) with
// idle VALU/BW pipes; the layer-1 GEMM (independent of degrees) overlaps it in
// the same dispatch via blockIdx partitioning. P1 is UNSCALED (out_norm unknown
// here); gather1 applies out_norm[src] per edge instead.
__global__ __launch_bounds__(256) void hist_gemm_kernel(
    const int* __restrict__ src, const int* __restrict__ dst,
    int* __restrict__ deg_src, int* __restrict__ deg_dst, int* __restrict__ slot,
    int E,
    const float* __restrict__ X, const float* __restrict__ W, float* __restrict__ P,
    int n, int gemm_blocks) {
    if ((int)blockIdx.x < gemm_blocks) {
        // ---- GEMM phase: P[row] = X[row] @ W ----
        int lane = threadIdx.x & 63;
        int wid = blockIdx.x * 4 + (threadIdx.x >> 6);
        int base = wid * 16;
        if (base >= n) return;
        float w[D];
#pragma unroll
        for (int k = 0; k < D; k++) w[k] = W[k * D + lane];
        int m = min(16, n - base);
        for (int i = 0; i < m; i++) {
            int row = base + i;
            const float* Xr = X + (size_t)__builtin_amdgcn_readfirstlane(row) * D;
            float o0 = 0.f, o1 = 0.f, o2 = 0.f, o3 = 0.f;
#pragma unroll
            for (int k = 0; k < D; k += 4) {
                o0 = fmaf(Xr[k + 0], w[k + 0], o0);
                o1 = fmaf(Xr[k + 1], w[k + 1], o1);
                o2 = fmaf(Xr[k + 2], w[k + 2], o2);
                o3 = fmaf(Xr[k + 3], w[k + 3], o3);
            }
            P[(size_t)row * D + lane] = (o0 + o1) + (o2 + o3);
        }
    } else {
        // ---- histogram phase ----
        int i = ((int)blockIdx.x - gemm_blocks) * (int)blockDim.x + (int)threadIdx.x;
        if (i < E) {
            atomicAdd(&deg_src[src[i]], 1);                 // fire-and-forget
            slot[i] = atomicAdd(&deg_dst[dst[i]], 1);       // return = CSR slot
        }
    }
}

// ---------------- scans ----------------

// Scan step 1: per-block (1024 elements) totals of deg_dst.
__global__ void scan1_kernel(const int* __restrict__ deg, int* __restrict__ blk_tot, int n) {
    __shared__ int sdata[256];
    int tid = threadIdx.x;
    int base = blockIdx.x * 1024 + tid * 4;
    int s = 0;
#pragma unroll
    for (int j = 0; j < 4; j++) {
        int idx = base + j;
        s += (idx < n) ? deg[idx] : 0;
    }
    sdata[tid] = s;
    __syncthreads();
    for (int off = 128; off > 0; off >>= 1) {
        if (tid < off) sdata[tid] += sdata[tid + off];
        __syncthreads();
    }
    if (tid == 0) blk_tot[blockIdx.x] = sdata[0];
}

// Scan step 2: exclusive scan of block totals (single block, nb <= 1024).
__global__ void scan2_kernel(int* __restrict__ blk_tot, int nb) {
    __shared__ int tmp[1024];
    int tid = threadIdx.x;
    int v = (tid < nb) ? blk_tot[tid] : 0;
    tmp[tid] = v;
    __syncthreads();
    int val = v;
    for (int off = 1; off < 1024; off <<= 1) {
        int add = (tid >= off) ? tmp[tid - off] : 0;
        __syncthreads();
        val += add;
        tmp[tid] = val;
        __syncthreads();
    }
    if (tid < nb) blk_tot[tid] = val - v;  // exclusive
}

// Scan step 3: write exclusive row_ptr, plus both degree norms (fused).
__global__ void scan3_norms_kernel(const int* __restrict__ deg_dst, const int* __restrict__ deg_src,
                                   const int* __restrict__ blk_tot, int* __restrict__ row_ptr,
                                   float* __restrict__ out_norm, float* __restrict__ in_norm,
                                   int n, int E) {
    __shared__ int sdata[256];
    int tid = threadIdx.x;
    int base = blockIdx.x * 1024 + tid * 4;
    int v[4];
    int s = 0;
#pragma unroll
    for (int j = 0; j < 4; j++) {
        int idx = base + j;
        v[j] = (idx < n) ? deg_dst[idx] : 0;
        s += v[j];
    }
    sdata[tid] = s;
    __syncthreads();
    int val = s;
    for (int off = 1; off < 256; off <<= 1) {
        int add = (tid >= off) ? sdata[tid - off] : 0;
        __syncthreads();
        val += add;
        sdata[tid] = val;
        __syncthreads();
    }
    int excl = blk_tot[blockIdx.x] + val - s;
#pragma unroll
    for (int j = 0; j < 4; j++) {
        int idx = base + j;
        if (idx < n) {
            row_ptr[idx] = excl;
            in_norm[idx] = rsqrtf((float)max(v[j], 1));
            out_norm[idx] = rsqrtf((float)max(deg_src[idx], 1));
        }
        excl += v[j];
    }
    if (blockIdx.x == 0 && tid == 0) row_ptr[n] = E;
}

// Atomic-free CSR fill. Streamed inputs use NT loads; the random 4B scatter uses
// an NT store to avoid the L2 write-allocate fetch (~64B line fetch per 4B write).
__global__ void fill_csr_kernel(const int* __restrict__ src, const int* __restrict__ dst,
                                const int* __restrict__ row_ptr, const int* __restrict__ slot,
                                int* __restrict__ csr_src, int E) {
    int i = blockIdx.x * blockDim.x + threadIdx.x;
    if (i < E) {
        int d = __builtin_nontemporal_load(&dst[i]);
        int s = __builtin_nontemporal_load(&src[i]);
        int sl = __builtin_nontemporal_load(&slot[i]);
        __builtin_nontemporal_store(s, &csr_src[row_ptr[d] + sl]);
    }
}

// ---------------- dense GEMM: Y[row] = X[row] @ W (layers 2,3) ----------------
__global__ __launch_bounds__(256) void gemm_kernel(
    const float* __restrict__ X, const float* __restrict__ W,
    float* __restrict__ Y, int n) {
    int lane = threadIdx.x & 63;
    int wid = blockIdx.x * 4 + (threadIdx.x >> 6);
    int base = wid * 16;
    if (base >= n) return;

    float w[D];
#pragma unroll
    for (int k = 0; k < D; k++) w[k] = W[k * D + lane];

    int m = min(16, n - base);
    for (int i = 0; i < m; i++) {
        int row = base + i;
        const float* Xr = X + (size_t)__builtin_amdgcn_readfirstlane(row) * D;
        float o0 = 0.f, o1 = 0.f, o2 = 0.f, o3 = 0.f;
#pragma unroll
        for (int k = 0; k < D; k += 4) {
            o0 = fmaf(Xr[k + 0], w[k + 0], o0);
            o1 = fmaf(Xr[k + 1], w[k + 1], o1);
            o2 = fmaf(Xr[k + 2], w[k + 2], o2);
            o3 = fmaf(Xr[k + 3], w[k + 3], o3);
        }
        Y[(size_t)row * D + lane] = (o0 + o1) + (o2 + o3);
    }
}

// ---------------- gather-sum: h[v] = post( in_norm[v] * sum_e on(e)*P[src(e)] + b ) ----------
// Wave per node; 4 edge-groups x 16 feature-lanes, float4/lane.
// SCALE_EDGES: multiply each gathered row by out_norm[src] (layer 1 only).
// RELU_SCALE : epilogue relu then pre-scale by out_norm[v] for next layer.
template <int SCALE_EDGES, int RELU_SCALE>
__global__ __launch_bounds__(256) void gather_kernel(
    const float4* __restrict__ P4, const int* __restrict__ csr_src,
    const int* __restrict__ row_ptr, const float* __restrict__ in_norm,
    const float* __restrict__ out_norm, const float* __restrict__ bias,
    float4* __restrict__ out4, int n) {
    int tid = threadIdx.x;
    int lane = tid & 63;
    int v = blockIdx.x * 4 + (tid >> 6);
    if (v >= n) return;

    int begin = row_ptr[v];
    int end = row_ptr[v + 1];
    int eg = lane >> 4;   // edge group 0..3
    int fl = lane & 15;   // float4 index within row

    float inv = in_norm[v];
    float sc = RELU_SCALE ? out_norm[v] : 1.f;
    float4 b4 = ((const float4*)bias)[fl];

    float4 acc0 = make_float4(0.f, 0.f, 0.f, 0.f);
    float4 acc1 = make_float4(0.f, 0.f, 0.f, 0.f);

    for (int base_e = begin; base_e < end; base_e += 16) {
        int e0 = base_e + eg;
        int e1 = e0 + 4;
        int e2 = e0 + 8;
        int e3 = e0 + 12;
        int j0 = (e0 < end) ? csr_src[e0] : -1;
        int j1 = (e1 < end) ? csr_src[e1] : -1;
        int j2 = (e2 < end) ? csr_src[e2] : -1;
        int j3 = (e3 < end) ? csr_src[e3] : -1;
        float on0 = 1.f, on1 = 1.f, on2 = 1.f, on3 = 1.f;
        if (SCALE_EDGES) {
            if (j0 >= 0) on0 = out_norm[j0];
            if (j1 >= 0) on1 = out_norm[j1];
            if (j2 >= 0) on2 = out_norm[j2];
            if (j3 >= 0) on3 = out_norm[j3];
        }
        if (j0 >= 0) {
            float4 a = P4[(size_t)j0 * 16 + fl];
            acc0.x = fmaf(a.x, on0, acc0.x); acc0.y = fmaf(a.y, on0, acc0.y);
            acc0.z = fmaf(a.z, on0, acc0.z); acc0.w = fmaf(a.w, on0, acc0.w);
        }
        if (j1 >= 0) {
            float4 a = P4[(size_t)j1 * 16 + fl];
            acc1.x = fmaf(a.x, on1, acc1.x); acc1.y = fmaf(a.y, on1, acc1.y);
            acc1.z = fmaf(a.z, on1, acc1.z); acc1.w = fmaf(a.w, on1, acc1.w);
        }
        if (j2 >= 0) {
            float4 a = P4[(size_t)j2 * 16 + fl];
            acc0.x = fmaf(a.x, on2, acc0.x); acc0.y = fmaf(a.y, on2, acc0.y);
            acc0.z = fmaf(a.z, on2, acc0.z); acc0.w = fmaf(a.w, on2, acc0.w);
        }
        if (j3 >= 0) {
            float4 a = P4[(size_t)j3 * 16 + fl];
            acc1.x = fmaf(a.x, on3, acc1.x); acc1.y = fmaf(a.y, on3, acc1.y);
            acc1.z = fmaf(a.z, on3, acc1.z); acc1.w = fmaf(a.w, on3, acc1.w);
        }
    }
    acc0.x += acc1.x; acc0.y += acc1.y; acc0.z += acc1.z; acc0.w += acc1.w;

    acc0.x += __shfl_down(acc0.x, 32); acc0.y += __shfl_down(acc0.y, 32);
    acc0.z += __shfl_down(acc0.z, 32); acc0.w += __shfl_down(acc0.w, 32);
    acc0.x += __shfl_down(acc0.x, 16); acc0.y += __shfl_down(acc0.y, 16);
    acc0.z += __shfl_down(acc0.z, 16); acc0.w += __shfl_down(acc0.w, 16);

    if (eg == 0) {
        float4 o;
        o.x = fmaf(acc0.x, inv, b4.x);
        o.y = fmaf(acc0.y, inv, b4.y);
        o.z = fmaf(acc0.z, inv, b4.z);
        o.w = fmaf(acc0.w, inv, b4.w);
        if (RELU_SCALE) {
            o.x = fmaxf(o.x, 0.f) * sc;
            o.y = fmaxf(o.y, 0.f) * sc;
            o.z = fmaxf(o.z, 0.f) * sc;
            o.w = fmaxf(o.w, 0.f) * sc;
        }
        out4[(size_t)v * 16 + fl] = o;
    }
}

// ---------------- launch ----------------

extern "C" void kernel_launch(void* const* d_in, const int* in_sizes, int n_in,
                              void* d_out, int out_size, void* d_ws, size_t ws_size,
                              hipStream_t stream) {
    const float* x  = (const float*)d_in[0];
    const int* src  = (const int*)d_in[1];
    const int* dst  = (const int*)d_in[2];
    const float* W1 = (const float*)d_in[3];
    const float* b1 = (const float*)d_in[4];
    const float* W2 = (const float*)d_in[5];
    const float* b2 = (const float*)d_in[6];
    const float* W3 = (const float*)d_in[7];
    const float* b3 = (const float*)d_in[8];

    const int N = in_sizes[0] / D;
    const int E = in_sizes[1];

    char* ws = (char*)d_ws;
    size_t off = 0;
    auto alloc = [&](size_t elems) -> void* {
        void* p = (void*)(ws + off);
        off += ((elems + 3) / 4) * 16;  // pad to 16B
        return p;
    };
    int* deg_src   = (int*)alloc(N);   // contiguous with deg_dst for one memset
    int* deg_dst   = (int*)alloc(N);
    int* row_ptr   = (int*)alloc(N + 1);
    int* blk_tot   = (int*)alloc(1024);
    float* out_nrm = (float*)alloc(N);
    float* in_nrm  = (float*)alloc(N);
    int* slot      = (int*)alloc(E);
    int* csr_src   = (int*)alloc(E);
    float* bufP    = (float*)alloc((size_t)N * D);  // transformed features
    float* bufH    = (float*)alloc((size_t)N * D);  // hidden state

    const int B = 256;
    hipMemsetAsync(deg_src, 0, (size_t)2 * N * sizeof(int), stream);

    // fused: gemm blocks first (start filling CUs), hist blocks behind
    int ggrid = ((N + 15) / 16 + 3) / 4;
    int hgrid = (E + B - 1) / B;
    hist_gemm_kernel<<<ggrid + hgrid, B, 0, stream>>>(src, dst, deg_src, deg_dst,
                                                      slot, E, x, W1, bufP, N, ggrid);

    int nb = (N + 1023) / 1024;
    scan1_kernel<<<nb, 256, 0, stream>>>(deg_dst, blk_tot, N);
    scan2_kernel<<<1, 1024, 0, stream>>>(blk_tot, nb);
    scan3_norms_kernel<<<nb, 256, 0, stream>>>(deg_dst, deg_src, blk_tot, row_ptr,
                                               out_nrm, in_nrm, N, E);

    fill_csr_kernel<<<(E + B - 1) / B, B, 0, stream>>>(src, dst, row_ptr, slot,
                                                       csr_src, E);

    int sgrid = (N + 3) / 4;  // 1 node/wave, 4 waves/block

    // layer 1: P1 unscaled -> gather applies out_norm[src] per edge
    gather_kernel<1, 1><<<sgrid, 256, 0, stream>>>((const float4*)bufP, csr_src, row_ptr,
                                                   in_nrm, out_nrm, b1, (float4*)bufH, N);
    // layer 2: h1 already carries out_norm
    gemm_kernel<<<ggrid, 256, 0, stream>>>(bufH, W2, bufP, N);
    gather_kernel<0, 1><<<sgrid, 256, 0, stream>>>((const float4*)bufP, csr_src, row_ptr,
                                                   in_nrm, out_nrm, b2, (float4*)bufH, N);
    // layer 3: final — no relu, no pre-scale
    gemm_kernel<<<ggrid, 256, 0, stream>>>(bufH, W3, bufP, N);
    gather_kernel<0, 0><<<sgrid, 256, 0, stream>>>((const float4*)bufP, csr_src, row_ptr,
                                                   in_nrm, out_nrm, b3, (float4*)d_out, N);
}